// Round 20
// baseline (157.834 us; speedup 1.0000x reference)
//
#include <hip/hip_runtime.h>

#define H 1024
#define B_ 4
#define T_ 512
#define NCTX 2048
#define NH 16
#define HD 64

typedef __attribute__((ext_vector_type(8))) short bf16x8;
typedef __attribute__((ext_vector_type(4))) float f32x4;
typedef __attribute__((ext_vector_type(4))) short s16x4;

__device__ __forceinline__ ushort f2b(float f) {
  union { float f; unsigned u; } v; v.f = f;
  unsigned u = v.u;
  unsigned r = (u + 0x7FFFu + ((u >> 16) & 1u)) >> 16;
  return (ushort)r;
}

__device__ __forceinline__ unsigned cvt_pk_bf16(float lo, float hi) {
  unsigned r;
  asm("v_cvt_pk_bf16_f32 %0, %1, %2" : "=v"(r) : "v"(lo), "v"(hi));
  return r;
}

__device__ __forceinline__ void gld16(const void* g, void* l) {
  __builtin_amdgcn_global_load_lds((const __attribute__((address_space(1))) unsigned int*)g,
                                   (__attribute__((address_space(3))) unsigned int*)l, 16, 0, 0);
}

// ---------------- fused prep (cvt x4 + q-embed + ctx-embed + mask), grid-strided ----------------

__global__ void prep_all(const float* __restrict__ query, const float* __restrict__ ctx,
                         const int* __restrict__ ids, const int* __restrict__ curp,
                         const int* __restrict__ bars,
                         const float* __restrict__ iemb, const float* __restrict__ bemb,
                         const float* __restrict__ Wq, const float* __restrict__ Wk,
                         const float* __restrict__ Wv, const float* __restrict__ Wo,
                         ushort* __restrict__ qin, ushort* __restrict__ ctxb,
                         ushort* __restrict__ Wqb, ushort* __restrict__ Wkb,
                         ushort* __restrict__ Wvb, ushort* __restrict__ Wob,
                         float* __restrict__ maskf) {
  for (int blk = blockIdx.x; blk < 14368; blk += gridDim.x) {
    if (blk < 8192) {
      int i = blk * 256 + threadIdx.x;
      int row = i >> 8;
      int c4 = i & 255;
      int id = ids[row];
      int bar = bars[row];
      bar = bar < 0 ? 0 : (bar > 7 ? 7 : bar);
      float4 v = ((const float4*)ctx)[i];
      float4 e = ((const float4*)(iemb + (size_t)id * H))[c4];
      float4 g = ((const float4*)(bemb + (size_t)bar * H))[c4];
      s16x4 o;
      o[0] = (short)f2b(v.x + e.x + g.x); o[1] = (short)f2b(v.y + e.y + g.y);
      o[2] = (short)f2b(v.z + e.z + g.z); o[3] = (short)f2b(v.w + e.w + g.w);
      ((s16x4*)ctxb)[i] = o;
    } else if (blk < 10240) {
      int cur = curp[0];
      int i = (blk - 8192) * 256 + threadIdx.x;
      int c4 = i & 255;
      float4 v = ((const float4*)query)[i];
      float4 e = ((const float4*)(iemb + (size_t)cur * H))[c4];
      s16x4 o;
      o[0] = (short)f2b(v.x + e.x); o[1] = (short)f2b(v.y + e.y);
      o[2] = (short)f2b(v.z + e.z); o[3] = (short)f2b(v.w + e.w);
      ((s16x4*)qin)[i] = o;
    } else if (blk < 14336) {
      int b2 = blk - 10240;
      int which = b2 >> 10;
      int i = (b2 & 1023) * 256 + threadIdx.x;
      const float* s = which == 0 ? Wq : which == 1 ? Wk : which == 2 ? Wv : Wo;
      ushort* d = which == 0 ? Wqb : which == 1 ? Wkb : which == 2 ? Wvb : Wob;
      float4 v = ((const float4*)s)[i];
      s16x4 o;
      o[0] = (short)f2b(v.x); o[1] = (short)f2b(v.y);
      o[2] = (short)f2b(v.z); o[3] = (short)f2b(v.w);
      ((s16x4*)d)[i] = o;
    } else {
      int cur = curp[0];
      int i = (blk - 14336) * 256 + threadIdx.x;
      maskf[i] = (ids[i] != cur) ? 0.f : -1e30f;
    }
  }
}

// ---------------- fused projection GEMM (Q + K + V), 2-phase double-buffered ----------------
// Q prescale = 0.125 * log2(e): scores land in base-2 domain for exp2-based softmax.

__global__ __launch_bounds__(256) void proj_k(const ushort* __restrict__ Aq,
                                              const ushort* __restrict__ Actx,
                                              const ushort* __restrict__ WQ,
                                              const ushort* __restrict__ WK,
                                              const ushort* __restrict__ WV,
                                              const float* __restrict__ bQ,
                                              const float* __restrict__ bK,
                                              const float* __restrict__ bV,
                                              ushort* __restrict__ Qout,
                                              ushort* __restrict__ Kout,
                                              ushort* __restrict__ VTout) {
  const int id = blockIdx.x;
  const ushort* A;
  const ushort* W;
  const float* bias;
  int row0, col0, mode;  // 0: bf16 row-major (K); 1: VT; 2: bf16 *0.125*log2e (Q)
  ushort* Cout;
  if (id < 1024) {
    int xcd = id & 7, rest = id >> 3;
    int bx = rest & 15, by = (rest >> 4) * 8 + xcd;
    A = Actx; row0 = by * 128;
    if (bx < 8) { W = WK; bias = bK; col0 = bx * 128; mode = 0; Cout = Kout; }
    else        { W = WV; bias = bV; col0 = (bx - 8) * 128; mode = 1; Cout = VTout; }
  } else {
    int q = id - 1024;
    A = Aq; row0 = (q >> 3) * 128; col0 = (q & 7) * 128;
    W = WQ; bias = bQ; mode = 2; Cout = Qout;
  }

  __shared__ ushort As[2][128 * 32];
  __shared__ ushort Bs[2][128 * 32];
  const int tid = threadIdx.x;
  const int lane = tid & 63;
  const int wv = tid >> 6;
  const int wr = wv >> 1, wc = wv & 1;
  const int lo = lane & 15, hi = lane >> 4;

  f32x4 acc[4][4];
#pragma unroll
  for (int m = 0; m < 4; m++)
#pragma unroll
    for (int n = 0; n < 4; n++) acc[m][n] = (f32x4){0.f, 0.f, 0.f, 0.f};

#pragma unroll
  for (int c = 0; c < 2; c++) {
    int ia = wv * 128 + c * 64 + lane;
    int r = ia >> 2, s = ia & 3;
    gld16(A + (size_t)(row0 + r) * H + s * 8, (char*)As[0] + (wv * 128 + c * 64) * 16);
    gld16(W + (size_t)(col0 + r) * H + s * 8, (char*)Bs[0] + (wv * 128 + c * 64) * 16);
  }
  __syncthreads();

  int cur = 0;
  for (int kt = 0; kt < 32; kt++) {
    if (kt < 31) {
#pragma unroll
      for (int c = 0; c < 2; c++) {
        int ia = wv * 128 + c * 64 + lane;
        int r = ia >> 2, s = ia & 3;
        gld16(A + (size_t)(row0 + r) * H + (kt + 1) * 32 + s * 8,
              (char*)As[cur ^ 1] + (wv * 128 + c * 64) * 16);
        gld16(W + (size_t)(col0 + r) * H + (kt + 1) * 32 + s * 8,
              (char*)Bs[cur ^ 1] + (wv * 128 + c * 64) * 16);
      }
    }
    bf16x8 af[4], bfr[4];
#pragma unroll
    for (int m = 0; m < 4; m++) af[m] = *(const bf16x8*)(As[cur] + (wr * 64 + m * 16 + lo) * 32 + hi * 8);
#pragma unroll
    for (int n = 0; n < 4; n++) bfr[n] = *(const bf16x8*)(Bs[cur] + (wc * 64 + n * 16 + lo) * 32 + hi * 8);
#pragma unroll
    for (int m = 0; m < 4; m++)
#pragma unroll
      for (int n = 0; n < 4; n++)
        acc[m][n] = __builtin_amdgcn_mfma_f32_16x16x32_bf16(af[m], bfr[n], acc[m][n], 0, 0, 0);
    __syncthreads();
    cur ^= 1;
  }

#pragma unroll
  for (int m = 0; m < 4; m++) {
    int gr0 = row0 + wr * 64 + m * 16 + hi * 4;
#pragma unroll
    for (int n = 0; n < 4; n++) {
      int gc = col0 + wc * 64 + n * 16 + lo;
      float bv = bias[gc];
      if (mode == 0) {
#pragma unroll
        for (int r = 0; r < 4; r++)
          Cout[(size_t)(gr0 + r) * H + gc] = f2b(acc[m][n][r] + bv);
      } else if (mode == 1) {
        int bb = gr0 >> 11, n0 = gr0 & 2047;
        s16x4 o;
#pragma unroll
        for (int r = 0; r < 4; r++) o[r] = (short)f2b(acc[m][n][r] + bv);
        *(s16x4*)(Cout + (size_t)bb * (H * NCTX) + (size_t)gc * NCTX + n0) = o;
      } else {
#pragma unroll
        for (int r = 0; r < 4; r++)
          Cout[(size_t)(gr0 + r) * H + gc] = f2b((acc[m][n][r] + bv) * 0.18033688f);  // 0.125*log2(e)
      }
    }
  }
}

// ---------------- out-projection GEMM (f32 out), 2-phase ----------------

__global__ __launch_bounds__(256) void gemm_o(const ushort* __restrict__ A,
                                              const ushort* __restrict__ W,
                                              const float* __restrict__ bias,
                                              float* __restrict__ Cout) {
  __shared__ ushort As[2][128 * 32];
  __shared__ ushort Bs[2][128 * 32];
  const int tid = threadIdx.x;
  const int lane = tid & 63;
  const int wv = tid >> 6;
  const int wr = wv >> 1, wc = wv & 1;
  const int lo = lane & 15, hi = lane >> 4;
  const int row0 = blockIdx.y * 128, col0 = blockIdx.x * 128;

  f32x4 acc[4][4];
#pragma unroll
  for (int m = 0; m < 4; m++)
#pragma unroll
    for (int n = 0; n < 4; n++) acc[m][n] = (f32x4){0.f, 0.f, 0.f, 0.f};

#pragma unroll
  for (int c = 0; c < 2; c++) {
    int ia = wv * 128 + c * 64 + lane;
    int r = ia >> 2, s = ia & 3;
    gld16(A + (size_t)(row0 + r) * H + s * 8, (char*)As[0] + (wv * 128 + c * 64) * 16);
    gld16(W + (size_t)(col0 + r) * H + s * 8, (char*)Bs[0] + (wv * 128 + c * 64) * 16);
  }
  __syncthreads();

  int cur = 0;
  for (int kt = 0; kt < 32; kt++) {
    if (kt < 31) {
#pragma unroll
      for (int c = 0; c < 2; c++) {
        int ia = wv * 128 + c * 64 + lane;
        int r = ia >> 2, s = ia & 3;
        gld16(A + (size_t)(row0 + r) * H + (kt + 1) * 32 + s * 8,
              (char*)As[cur ^ 1] + (wv * 128 + c * 64) * 16);
        gld16(W + (size_t)(col0 + r) * H + (kt + 1) * 32 + s * 8,
              (char*)Bs[cur ^ 1] + (wv * 128 + c * 64) * 16);
      }
    }
    bf16x8 af[4], bfr[4];
#pragma unroll
    for (int m = 0; m < 4; m++) af[m] = *(const bf16x8*)(As[cur] + (wr * 64 + m * 16 + lo) * 32 + hi * 8);
#pragma unroll
    for (int n = 0; n < 4; n++) bfr[n] = *(const bf16x8*)(Bs[cur] + (wc * 64 + n * 16 + lo) * 32 + hi * 8);
#pragma unroll
    for (int m = 0; m < 4; m++)
#pragma unroll
      for (int n = 0; n < 4; n++)
        acc[m][n] = __builtin_amdgcn_mfma_f32_16x16x32_bf16(af[m], bfr[n], acc[m][n], 0, 0, 0);
    __syncthreads();
    cur ^= 1;
  }

#pragma unroll
  for (int m = 0; m < 4; m++) {
    int gr0 = row0 + wr * 64 + m * 16 + hi * 4;
#pragma unroll
    for (int n = 0; n < 4; n++) {
      int gc = col0 + wc * 64 + n * 16 + lo;
      float bv = bias[gc];
#pragma unroll
      for (int r = 0; r < 4; r++)
        Cout[(size_t)(gr0 + r) * H + gc] = acc[m][n][r] + bv;
    }
  }
}

// ---------------- flash attention, KV-split 2, KVBLK=128, base-2 softmax ----------------
// Scores arrive pre-scaled by 0.125*log2(e); softmax uses exp2f (bare v_exp_f32, no ln2 mul).
// mrow/mlf are in the base-2 domain; combine uses exp2f accordingly.

#define NSPLIT 2
#define KVLEN (NCTX / NSPLIT)   // 1024
#define NT_KV (KVLEN / 128)     // 8

__global__ __launch_bounds__(256) void attn_k(const ushort* __restrict__ Q,
                                              const ushort* __restrict__ K,
                                              const ushort* __restrict__ VT,
                                              const float* __restrict__ maskf,
                                              float* __restrict__ OPf,
                                              float* __restrict__ mlf) {
  __shared__ ushort Ks[2][64 * 64];  // [sub-tile][kv][d]
  __shared__ ushort Vs[2][64 * 64];  // [sub-tile][d][kv]
  __shared__ ushort Ps[4][16 * 64];  // [wave][q][kv], shared across sub-tiles
  const int blk = (blockIdx.x & 7) * 128 + (blockIdx.x >> 3);  // XCD-chunked remap
  const int qt = blk & 7;
  const int h = (blk >> 3) & 15;
  const int b = (blk >> 7) & 3;
  const int p = blk >> 9;
  const int tid = threadIdx.x, lane = tid & 63, w = tid >> 6;
  const int lo = lane & 15, hi = lane >> 4;
  const int swz = (lo & 7) << 4;
  const int kvbase = p * KVLEN;

  const ushort* Qp = Q + ((size_t)(b * T_ + qt * 64 + w * 16 + lo)) * H + h * HD;
  bf16x8 qf0 = *(const bf16x8*)(Qp + hi * 8);
  bf16x8 qf1 = *(const bf16x8*)(Qp + 32 + hi * 8);

  f32x4 oacc[4];
#pragma unroll
  for (int d = 0; d < 4; d++) oacc[d] = (f32x4){0.f, 0.f, 0.f, 0.f};
  float mrow = -1e30f, lrow = 0.f;

  const float* maskb = maskf + b * NCTX;
  const ushort* Kbase = K + ((size_t)(b * NCTX)) * H + h * HD;
  const ushort* Vbase = VT + (size_t)b * (H * NCTX) + (size_t)(h * HD) * NCTX;

  const int sr = tid >> 3, ss = tid & 7;
  const int wb0 = (sr * 128 + ss * 16) ^ ((sr & 7) << 4);
  const int sr1 = (tid + 256) >> 3, ss1 = (tid + 256) & 7;
  const int wb1 = (sr1 * 128 + ss1 * 16) ^ ((sr1 & 7) << 4);

  bf16x8 kr[2][2], vr[2][2];  // [sub-tile][chunk]
#pragma unroll
  for (int j = 0; j < 2; j++) {
    int kv0 = kvbase + j * 64;
    kr[j][0] = *(const bf16x8*)(Kbase + (size_t)(kv0 + sr) * H + ss * 8);
    kr[j][1] = *(const bf16x8*)(Kbase + (size_t)(kv0 + sr1) * H + ss1 * 8);
    vr[j][0] = *(const bf16x8*)(Vbase + (size_t)sr * NCTX + kv0 + ss * 8);
    vr[j][1] = *(const bf16x8*)(Vbase + (size_t)sr1 * NCTX + kv0 + ss1 * 8);
  }
#pragma unroll
  for (int j = 0; j < 2; j++) {
    *(bf16x8*)((char*)Ks[j] + wb0) = kr[j][0];
    *(bf16x8*)((char*)Ks[j] + wb1) = kr[j][1];
    *(bf16x8*)((char*)Vs[j] + wb0) = vr[j][0];
    *(bf16x8*)((char*)Vs[j] + wb1) = vr[j][1];
  }
  __syncthreads();

  for (int t = 0; t < NT_KV; t++) {
    int kvt = kvbase + t * 128;
    if (t < NT_KV - 1) {  // T14: issue next 128-tile's loads early
#pragma unroll
      for (int j = 0; j < 2; j++) {
        int kv0 = kvt + 128 + j * 64;
        kr[j][0] = *(const bf16x8*)(Kbase + (size_t)(kv0 + sr) * H + ss * 8);
        kr[j][1] = *(const bf16x8*)(Kbase + (size_t)(kv0 + sr1) * H + ss1 * 8);
        vr[j][0] = *(const bf16x8*)(Vbase + (size_t)sr * NCTX + kv0 + ss * 8);
        vr[j][1] = *(const bf16x8*)(Vbase + (size_t)sr1 * NCTX + kv0 + ss1 * 8);
      }
    }

    // QK^T on both sub-tiles (swapped operands; lane: q=lo, kv=j*64+nt*16+hi*4+r)
    f32x4 sc[2][4];
    __builtin_amdgcn_s_setprio(1);
#pragma unroll
    for (int j = 0; j < 2; j++)
#pragma unroll
      for (int nt = 0; nt < 4; nt++) {
        bf16x8 kf0 = *(const bf16x8*)((char*)Ks[j] + ((((nt * 16 + lo) * 128) + hi * 16) ^ swz));
        bf16x8 kf1 = *(const bf16x8*)((char*)Ks[j] + ((((nt * 16 + lo) * 128) + 64 + hi * 16) ^ swz));
        f32x4 z = (f32x4){0.f, 0.f, 0.f, 0.f};
        z = __builtin_amdgcn_mfma_f32_16x16x32_bf16(kf0, qf0, z, 0, 0, 0);
        sc[j][nt] = __builtin_amdgcn_mfma_f32_16x16x32_bf16(kf1, qf1, z, 0, 0, 0);
      }
    __builtin_amdgcn_s_setprio(0);

    // additive mask
    float pv[2][4][4];
#pragma unroll
    for (int j = 0; j < 2; j++)
#pragma unroll
      for (int nt = 0; nt < 4; nt++) {
        float4 mv = *(const float4*)(maskb + kvt + j * 64 + nt * 16 + hi * 4);
        pv[j][nt][0] = sc[j][nt][0] + mv.x;
        pv[j][nt][1] = sc[j][nt][1] + mv.y;
        pv[j][nt][2] = sc[j][nt][2] + mv.z;
        pv[j][nt][3] = sc[j][nt][3] + mv.w;
      }

    // ONE online-softmax reduce over all 32 values (base-2 domain)
    float gm[2];
#pragma unroll
    for (int j = 0; j < 2; j++) {
      float m0 = fmaxf(fmaxf(pv[j][0][0], pv[j][0][1]), fmaxf(pv[j][0][2], pv[j][0][3]));
      float m1 = fmaxf(fmaxf(pv[j][1][0], pv[j][1][1]), fmaxf(pv[j][1][2], pv[j][1][3]));
      float m2 = fmaxf(fmaxf(pv[j][2][0], pv[j][2][1]), fmaxf(pv[j][2][2], pv[j][2][3]));
      float m3 = fmaxf(fmaxf(pv[j][3][0], pv[j][3][1]), fmaxf(pv[j][3][2], pv[j][3][3]));
      gm[j] = fmaxf(fmaxf(m0, m1), fmaxf(m2, m3));
    }
    float x = fmaxf(gm[0], gm[1]);
    x = fmaxf(x, __shfl_xor(x, 16));
    x = fmaxf(x, __shfl_xor(x, 32));
    bool defer = __all((x <= mrow + 8.0f) && (mrow > -1e29f));
    float mn, scal = 1.f;
    if (defer) {
      mn = mrow;
    } else {
      mn = fmaxf(mrow, x);
      scal = exp2f(mrow - mn);
      mrow = mn;
    }
    float rs = 0.f;
#pragma unroll
    for (int j = 0; j < 2; j++) {
      float rsp[4];
#pragma unroll
      for (int nt = 0; nt < 4; nt++) {
        float e0 = exp2f(pv[j][nt][0] - mn);
        float e1 = exp2f(pv[j][nt][1] - mn);
        float e2 = exp2f(pv[j][nt][2] - mn);
        float e3 = exp2f(pv[j][nt][3] - mn);
        pv[j][nt][0] = e0; pv[j][nt][1] = e1; pv[j][nt][2] = e2; pv[j][nt][3] = e3;
        rsp[nt] = (e0 + e1) + (e2 + e3);
      }
      rs += (rsp[0] + rsp[1]) + (rsp[2] + rsp[3]);
    }
    rs += __shfl_xor(rs, 16);
    rs += __shfl_xor(rs, 32);
    if (defer) {
      lrow += rs;
    } else {
      lrow = lrow * scal + rs;
      float sq0 = __shfl(scal, hi * 4 + 0);
      float sq1 = __shfl(scal, hi * 4 + 1);
      float sq2 = __shfl(scal, hi * 4 + 2);
      float sq3 = __shfl(scal, hi * 4 + 3);
#pragma unroll
      for (int d = 0; d < 4; d++) {
        oacc[d][0] *= sq0; oacc[d][1] *= sq1; oacc[d][2] *= sq2; oacc[d][3] *= sq3;
      }
    }

    // per sub-tile: P -> shared per-wave Ps, then PV (same-wave sequential, no barrier)
    __builtin_amdgcn_s_setprio(1);
#pragma unroll
    for (int j = 0; j < 2; j++) {
#pragma unroll
      for (int nt = 0; nt < 4; nt++) {
        uint2 pw;
        pw.x = cvt_pk_bf16(pv[j][nt][0], pv[j][nt][1]);
        pw.y = cvt_pk_bf16(pv[j][nt][2], pv[j][nt][3]);
        *(uint2*)((char*)Ps[w] + ((lo * 128 + (nt * 16 + hi * 4) * 2) ^ swz)) = pw;
      }
#pragma unroll
      for (int ks = 0; ks < 2; ks++) {
        bf16x8 pa = *(const bf16x8*)((char*)Ps[w] + ((lo * 128 + (ks * 64 + hi * 16)) ^ swz));
#pragma unroll
        for (int d = 0; d < 4; d++) {
          bf16x8 vf = *(const bf16x8*)((char*)Vs[j] + (((d * 16 + lo) * 128 + ks * 64 + hi * 16) ^ swz));
          oacc[d] = __builtin_amdgcn_mfma_f32_16x16x32_bf16(pa, vf, oacc[d], 0, 0, 0);
        }
      }
    }
    __builtin_amdgcn_s_setprio(0);

    if (t < NT_KV - 1) {
      __syncthreads();  // all waves done reading this 128-tile
#pragma unroll
      for (int j = 0; j < 2; j++) {
        *(bf16x8*)((char*)Ks[j] + wb0) = kr[j][0];
        *(bf16x8*)((char*)Ks[j] + wb1) = kr[j][1];
        *(bf16x8*)((char*)Vs[j] + wb0) = vr[j][0];
        *(bf16x8*)((char*)Vs[j] + wb1) = vr[j][1];
      }
      __syncthreads();  // writes visible before next iteration's reads
    }
  }

  int row0 = b * 512 + qt * 64 + w * 16 + hi * 4;
#pragma unroll
  for (int d = 0; d < 4; d++) {
#pragma unroll
    for (int r = 0; r < 4; r++)
      OPf[((size_t)p * 2048 + row0 + r) * 1024 + h * 64 + d * 16 + lo] = oacc[d][r];
  }
  if (hi == 0) {
    int qrow = b * 512 + qt * 64 + w * 16 + lo;
    mlf[(((size_t)p * 2048 + qrow) * 16 + h) * 2] = mrow;
    mlf[(((size_t)p * 2048 + qrow) * 16 + h) * 2 + 1] = lrow;
  }
}

__global__ void attn_combine(const float* __restrict__ OPf, const float* __restrict__ mlf,
                             ushort* __restrict__ O) {
  int idx = blockIdx.x * 256 + threadIdx.x;
  int btr = idx >> 8;
  int c4 = idx & 255;
  int h = c4 >> 4;
  float m0 = mlf[((size_t)btr * 16 + h) * 2];
  float l0 = mlf[((size_t)btr * 16 + h) * 2 + 1];
  float m1 = mlf[(((size_t)2048 + btr) * 16 + h) * 2];
  float l1 = mlf[(((size_t)2048 + btr) * 16 + h) * 2 + 1];
  float M = fmaxf(m0, m1);
  float a0 = exp2f(m0 - M), a1 = exp2f(m1 - M);  // base-2 domain
  float inv = 1.0f / (a0 * l0 + a1 * l1);
  float4 o0 = ((const float4*)OPf)[idx];
  float4 o1 = ((const float4*)OPf)[(size_t)524288 + idx];
  s16x4 r;
  r[0] = (short)f2b((a0 * o0.x + a1 * o1.x) * inv);
  r[1] = (short)f2b((a0 * o0.y + a1 * o1.y) * inv);
  r[2] = (short)f2b((a0 * o0.z + a1 * o1.z) * inv);
  r[3] = (short)f2b((a0 * o0.w + a1 * o1.w) * inv);
  ((s16x4*)O)[idx] = r;
}

// ---------------- launch ----------------

extern "C" void kernel_launch(void* const* d_in, const int* in_sizes, int n_in,
                              void* d_out, int out_size, void* d_ws, size_t ws_size,
                              hipStream_t stream) {
  const float* query = (const float*)d_in[0];
  const float* context = (const float*)d_in[1];
  const int* ids = (const int*)d_in[2];
  const int* curp = (const int*)d_in[3];
  const int* bars = (const int*)d_in[4];
  const float* Wq = (const float*)d_in[5];
  const float* bq = (const float*)d_in[6];
  const float* Wk = (const float*)d_in[7];
  const float* bk = (const float*)d_in[8];
  const float* Wv = (const float*)d_in[9];
  const float* bv = (const float*)d_in[10];
  const float* Wo = (const float*)d_in[11];
  const float* bo = (const float*)d_in[12];
  const float* iemb = (const float*)d_in[13];
  const float* bemb = (const float*)d_in[14];
  float* out = (float*)d_out;

  ushort* ws = (ushort*)d_ws;
  ushort* Wqb = ws;
  ushort* Wkb = Wqb + (1u << 20);
  ushort* Wvb = Wkb + (1u << 20);
  ushort* Wob = Wvb + (1u << 20);
  ushort* qin = Wob + (1u << 20);        // dead after proj -> mlf overlay
  ushort* ctxb = qin + (2u << 20);       // dead after proj -> OPf overlay
  ushort* Qb = ctxb + (8u << 20);
  ushort* Kb = Qb + (2u << 20);
  ushort* VTb = Kb + (8u << 20);
  ushort* AOb = VTb + (8u << 20);

  float* OPf = (float*)ctxb;  // 2 x 2048 x 1024 f32 = 16 MB
  float* mlf = (float*)qin;   // 2 x 2048 x 16 x 2 f32 = 512 KB
  float* maskf = out;         // d_out as scratch; overwritten by gemm_o at the end

  prep_all<<<2048, 256, 0, stream>>>(query, context, ids, curp, bars, iemb, bemb,
                                     Wq, Wk, Wv, Wo, qin, ctxb, Wqb, Wkb, Wvb, Wob, maskf);

  proj_k<<<1152, 256, 0, stream>>>(qin, ctxb, Wqb, Wkb, Wvb, bq, bk, bv, Qb, Kb, VTb);

  attn_k<<<1024, 256, 0, stream>>>(Qb, Kb, VTb, maskf, OPf, mlf);
  attn_combine<<<2048, 256, 0, stream>>>(OPf, mlf, AOb);

  gemm_o<<<dim3(8, 16), 256, 0, stream>>>(AOb, Wob, bo, out);
}

// Round 21
// 152.790 us; speedup vs baseline: 1.0330x; 1.0330x over previous
//
#include <hip/hip_runtime.h>

#define H 1024
#define B_ 4
#define T_ 512
#define NCTX 2048
#define NH 16
#define HD 64

typedef __attribute__((ext_vector_type(8))) short bf16x8;
typedef __attribute__((ext_vector_type(4))) float f32x4;
typedef __attribute__((ext_vector_type(4))) short s16x4;

__device__ __forceinline__ ushort f2b(float f) {
  union { float f; unsigned u; } v; v.f = f;
  unsigned u = v.u;
  unsigned r = (u + 0x7FFFu + ((u >> 16) & 1u)) >> 16;
  return (ushort)r;
}

__device__ __forceinline__ unsigned cvt_pk_bf16(float lo, float hi) {
  unsigned r;
  asm("v_cvt_pk_bf16_f32 %0, %1, %2" : "=v"(r) : "v"(lo), "v"(hi));
  return r;
}

__device__ __forceinline__ void gld16(const void* g, void* l) {
  __builtin_amdgcn_global_load_lds((const __attribute__((address_space(1))) unsigned int*)g,
                                   (__attribute__((address_space(3))) unsigned int*)l, 16, 0, 0);
}

// ---------------- fused prep (cvt x4 + q-embed + ctx-embed + mask), grid-strided ----------------

__global__ void prep_all(const float* __restrict__ query, const float* __restrict__ ctx,
                         const int* __restrict__ ids, const int* __restrict__ curp,
                         const int* __restrict__ bars,
                         const float* __restrict__ iemb, const float* __restrict__ bemb,
                         const float* __restrict__ Wq, const float* __restrict__ Wk,
                         const float* __restrict__ Wv, const float* __restrict__ Wo,
                         ushort* __restrict__ qin, ushort* __restrict__ ctxb,
                         ushort* __restrict__ Wqb, ushort* __restrict__ Wkb,
                         ushort* __restrict__ Wvb, ushort* __restrict__ Wob,
                         float* __restrict__ maskf) {
  for (int blk = blockIdx.x; blk < 14368; blk += gridDim.x) {
    if (blk < 8192) {
      int i = blk * 256 + threadIdx.x;
      int row = i >> 8;
      int c4 = i & 255;
      int id = ids[row];
      int bar = bars[row];
      bar = bar < 0 ? 0 : (bar > 7 ? 7 : bar);
      float4 v = ((const float4*)ctx)[i];
      float4 e = ((const float4*)(iemb + (size_t)id * H))[c4];
      float4 g = ((const float4*)(bemb + (size_t)bar * H))[c4];
      s16x4 o;
      o[0] = (short)f2b(v.x + e.x + g.x); o[1] = (short)f2b(v.y + e.y + g.y);
      o[2] = (short)f2b(v.z + e.z + g.z); o[3] = (short)f2b(v.w + e.w + g.w);
      ((s16x4*)ctxb)[i] = o;
    } else if (blk < 10240) {
      int cur = curp[0];
      int i = (blk - 8192) * 256 + threadIdx.x;
      int c4 = i & 255;
      float4 v = ((const float4*)query)[i];
      float4 e = ((const float4*)(iemb + (size_t)cur * H))[c4];
      s16x4 o;
      o[0] = (short)f2b(v.x + e.x); o[1] = (short)f2b(v.y + e.y);
      o[2] = (short)f2b(v.z + e.z); o[3] = (short)f2b(v.w + e.w);
      ((s16x4*)qin)[i] = o;
    } else if (blk < 14336) {
      int b2 = blk - 10240;
      int which = b2 >> 10;
      int i = (b2 & 1023) * 256 + threadIdx.x;
      const float* s = which == 0 ? Wq : which == 1 ? Wk : which == 2 ? Wv : Wo;
      ushort* d = which == 0 ? Wqb : which == 1 ? Wkb : which == 2 ? Wvb : Wob;
      float4 v = ((const float4*)s)[i];
      s16x4 o;
      o[0] = (short)f2b(v.x); o[1] = (short)f2b(v.y);
      o[2] = (short)f2b(v.z); o[3] = (short)f2b(v.w);
      ((s16x4*)d)[i] = o;
    } else {
      int cur = curp[0];
      int i = (blk - 14336) * 256 + threadIdx.x;
      maskf[i] = (ids[i] != cur) ? 0.f : -1e30f;
    }
  }
}

// ---------------- fused projection GEMM (Q + K + V), 2-phase double-buffered ----------------

__global__ __launch_bounds__(256) void proj_k(const ushort* __restrict__ Aq,
                                              const ushort* __restrict__ Actx,
                                              const ushort* __restrict__ WQ,
                                              const ushort* __restrict__ WK,
                                              const ushort* __restrict__ WV,
                                              const float* __restrict__ bQ,
                                              const float* __restrict__ bK,
                                              const float* __restrict__ bV,
                                              ushort* __restrict__ Qout,
                                              ushort* __restrict__ Kout,
                                              ushort* __restrict__ VTout) {
  const int id = blockIdx.x;
  const ushort* A;
  const ushort* W;
  const float* bias;
  int row0, col0, mode;  // 0: bf16 row-major (K); 1: VT; 2: bf16 *0.125 (Q)
  ushort* Cout;
  if (id < 1024) {
    int xcd = id & 7, rest = id >> 3;
    int bx = rest & 15, by = (rest >> 4) * 8 + xcd;
    A = Actx; row0 = by * 128;
    if (bx < 8) { W = WK; bias = bK; col0 = bx * 128; mode = 0; Cout = Kout; }
    else        { W = WV; bias = bV; col0 = (bx - 8) * 128; mode = 1; Cout = VTout; }
  } else {
    int q = id - 1024;
    A = Aq; row0 = (q >> 3) * 128; col0 = (q & 7) * 128;
    W = WQ; bias = bQ; mode = 2; Cout = Qout;
  }

  __shared__ ushort As[2][128 * 32];
  __shared__ ushort Bs[2][128 * 32];
  const int tid = threadIdx.x;
  const int lane = tid & 63;
  const int wv = tid >> 6;
  const int wr = wv >> 1, wc = wv & 1;
  const int lo = lane & 15, hi = lane >> 4;

  f32x4 acc[4][4];
#pragma unroll
  for (int m = 0; m < 4; m++)
#pragma unroll
    for (int n = 0; n < 4; n++) acc[m][n] = (f32x4){0.f, 0.f, 0.f, 0.f};

#pragma unroll
  for (int c = 0; c < 2; c++) {
    int ia = wv * 128 + c * 64 + lane;
    int r = ia >> 2, s = ia & 3;
    gld16(A + (size_t)(row0 + r) * H + s * 8, (char*)As[0] + (wv * 128 + c * 64) * 16);
    gld16(W + (size_t)(col0 + r) * H + s * 8, (char*)Bs[0] + (wv * 128 + c * 64) * 16);
  }
  __syncthreads();

  int cur = 0;
  for (int kt = 0; kt < 32; kt++) {
    if (kt < 31) {
#pragma unroll
      for (int c = 0; c < 2; c++) {
        int ia = wv * 128 + c * 64 + lane;
        int r = ia >> 2, s = ia & 3;
        gld16(A + (size_t)(row0 + r) * H + (kt + 1) * 32 + s * 8,
              (char*)As[cur ^ 1] + (wv * 128 + c * 64) * 16);
        gld16(W + (size_t)(col0 + r) * H + (kt + 1) * 32 + s * 8,
              (char*)Bs[cur ^ 1] + (wv * 128 + c * 64) * 16);
      }
    }
    bf16x8 af[4], bfr[4];
#pragma unroll
    for (int m = 0; m < 4; m++) af[m] = *(const bf16x8*)(As[cur] + (wr * 64 + m * 16 + lo) * 32 + hi * 8);
#pragma unroll
    for (int n = 0; n < 4; n++) bfr[n] = *(const bf16x8*)(Bs[cur] + (wc * 64 + n * 16 + lo) * 32 + hi * 8);
#pragma unroll
    for (int m = 0; m < 4; m++)
#pragma unroll
      for (int n = 0; n < 4; n++)
        acc[m][n] = __builtin_amdgcn_mfma_f32_16x16x32_bf16(af[m], bfr[n], acc[m][n], 0, 0, 0);
    __syncthreads();
    cur ^= 1;
  }

#pragma unroll
  for (int m = 0; m < 4; m++) {
    int gr0 = row0 + wr * 64 + m * 16 + hi * 4;
#pragma unroll
    for (int n = 0; n < 4; n++) {
      int gc = col0 + wc * 64 + n * 16 + lo;
      float bv = bias[gc];
      if (mode == 0) {
#pragma unroll
        for (int r = 0; r < 4; r++)
          Cout[(size_t)(gr0 + r) * H + gc] = f2b(acc[m][n][r] + bv);
      } else if (mode == 1) {
        int bb = gr0 >> 11, n0 = gr0 & 2047;
        s16x4 o;
#pragma unroll
        for (int r = 0; r < 4; r++) o[r] = (short)f2b(acc[m][n][r] + bv);
        *(s16x4*)(Cout + (size_t)bb * (H * NCTX) + (size_t)gc * NCTX + n0) = o;
      } else {
#pragma unroll
        for (int r = 0; r < 4; r++)
          Cout[(size_t)(gr0 + r) * H + gc] = f2b((acc[m][n][r] + bv) * 0.125f);
      }
    }
  }
}

// ---------------- out-projection GEMM (f32 out), 2-phase ----------------

__global__ __launch_bounds__(256) void gemm_o(const ushort* __restrict__ A,
                                              const ushort* __restrict__ W,
                                              const float* __restrict__ bias,
                                              float* __restrict__ Cout) {
  __shared__ ushort As[2][128 * 32];
  __shared__ ushort Bs[2][128 * 32];
  const int tid = threadIdx.x;
  const int lane = tid & 63;
  const int wv = tid >> 6;
  const int wr = wv >> 1, wc = wv & 1;
  const int lo = lane & 15, hi = lane >> 4;
  const int row0 = blockIdx.y * 128, col0 = blockIdx.x * 128;

  f32x4 acc[4][4];
#pragma unroll
  for (int m = 0; m < 4; m++)
#pragma unroll
    for (int n = 0; n < 4; n++) acc[m][n] = (f32x4){0.f, 0.f, 0.f, 0.f};

#pragma unroll
  for (int c = 0; c < 2; c++) {
    int ia = wv * 128 + c * 64 + lane;
    int r = ia >> 2, s = ia & 3;
    gld16(A + (size_t)(row0 + r) * H + s * 8, (char*)As[0] + (wv * 128 + c * 64) * 16);
    gld16(W + (size_t)(col0 + r) * H + s * 8, (char*)Bs[0] + (wv * 128 + c * 64) * 16);
  }
  __syncthreads();

  int cur = 0;
  for (int kt = 0; kt < 32; kt++) {
    if (kt < 31) {
#pragma unroll
      for (int c = 0; c < 2; c++) {
        int ia = wv * 128 + c * 64 + lane;
        int r = ia >> 2, s = ia & 3;
        gld16(A + (size_t)(row0 + r) * H + (kt + 1) * 32 + s * 8,
              (char*)As[cur ^ 1] + (wv * 128 + c * 64) * 16);
        gld16(W + (size_t)(col0 + r) * H + (kt + 1) * 32 + s * 8,
              (char*)Bs[cur ^ 1] + (wv * 128 + c * 64) * 16);
      }
    }
    bf16x8 af[4], bfr[4];
#pragma unroll
    for (int m = 0; m < 4; m++) af[m] = *(const bf16x8*)(As[cur] + (wr * 64 + m * 16 + lo) * 32 + hi * 8);
#pragma unroll
    for (int n = 0; n < 4; n++) bfr[n] = *(const bf16x8*)(Bs[cur] + (wc * 64 + n * 16 + lo) * 32 + hi * 8);
#pragma unroll
    for (int m = 0; m < 4; m++)
#pragma unroll
      for (int n = 0; n < 4; n++)
        acc[m][n] = __builtin_amdgcn_mfma_f32_16x16x32_bf16(af[m], bfr[n], acc[m][n], 0, 0, 0);
    __syncthreads();
    cur ^= 1;
  }

#pragma unroll
  for (int m = 0; m < 4; m++) {
    int gr0 = row0 + wr * 64 + m * 16 + hi * 4;
#pragma unroll
    for (int n = 0; n < 4; n++) {
      int gc = col0 + wc * 64 + n * 16 + lo;
      float bv = bias[gc];
#pragma unroll
      for (int r = 0; r < 4; r++)
        Cout[(size_t)(gr0 + r) * H + gc] = acc[m][n][r] + bv;
    }
  }
}

// ---------------- flash attention, KV-split 2, KVBLK=128, shared per-wave Ps ----------------

#define NSPLIT 2
#define KVLEN (NCTX / NSPLIT)   // 1024
#define NT_KV (KVLEN / 128)     // 8

__global__ __launch_bounds__(256) void attn_k(const ushort* __restrict__ Q,
                                              const ushort* __restrict__ K,
                                              const ushort* __restrict__ VT,
                                              const float* __restrict__ maskf,
                                              float* __restrict__ OPf,
                                              float* __restrict__ mlf) {
  __shared__ ushort Ks[2][64 * 64];  // [sub-tile][kv][d]
  __shared__ ushort Vs[2][64 * 64];  // [sub-tile][d][kv]
  __shared__ ushort Ps[4][16 * 64];  // [wave][q][kv], shared across sub-tiles
  const int blk = (blockIdx.x & 7) * 128 + (blockIdx.x >> 3);  // XCD-chunked remap
  const int qt = blk & 7;
  const int h = (blk >> 3) & 15;
  const int b = (blk >> 7) & 3;
  const int p = blk >> 9;
  const int tid = threadIdx.x, lane = tid & 63, w = tid >> 6;
  const int lo = lane & 15, hi = lane >> 4;
  const int swz = (lo & 7) << 4;
  const int kvbase = p * KVLEN;

  const ushort* Qp = Q + ((size_t)(b * T_ + qt * 64 + w * 16 + lo)) * H + h * HD;
  bf16x8 qf0 = *(const bf16x8*)(Qp + hi * 8);
  bf16x8 qf1 = *(const bf16x8*)(Qp + 32 + hi * 8);

  f32x4 oacc[4];
#pragma unroll
  for (int d = 0; d < 4; d++) oacc[d] = (f32x4){0.f, 0.f, 0.f, 0.f};
  float mrow = -1e30f, lrow = 0.f;

  const float* maskb = maskf + b * NCTX;
  const ushort* Kbase = K + ((size_t)(b * NCTX)) * H + h * HD;
  const ushort* Vbase = VT + (size_t)b * (H * NCTX) + (size_t)(h * HD) * NCTX;

  const int sr = tid >> 3, ss = tid & 7;
  const int wb0 = (sr * 128 + ss * 16) ^ ((sr & 7) << 4);
  const int sr1 = (tid + 256) >> 3, ss1 = (tid + 256) & 7;
  const int wb1 = (sr1 * 128 + ss1 * 16) ^ ((sr1 & 7) << 4);

  bf16x8 kr[2][2], vr[2][2];  // [sub-tile][chunk]
#pragma unroll
  for (int j = 0; j < 2; j++) {
    int kv0 = kvbase + j * 64;
    kr[j][0] = *(const bf16x8*)(Kbase + (size_t)(kv0 + sr) * H + ss * 8);
    kr[j][1] = *(const bf16x8*)(Kbase + (size_t)(kv0 + sr1) * H + ss1 * 8);
    vr[j][0] = *(const bf16x8*)(Vbase + (size_t)sr * NCTX + kv0 + ss * 8);
    vr[j][1] = *(const bf16x8*)(Vbase + (size_t)sr1 * NCTX + kv0 + ss1 * 8);
  }
#pragma unroll
  for (int j = 0; j < 2; j++) {
    *(bf16x8*)((char*)Ks[j] + wb0) = kr[j][0];
    *(bf16x8*)((char*)Ks[j] + wb1) = kr[j][1];
    *(bf16x8*)((char*)Vs[j] + wb0) = vr[j][0];
    *(bf16x8*)((char*)Vs[j] + wb1) = vr[j][1];
  }
  __syncthreads();

  for (int t = 0; t < NT_KV; t++) {
    int kvt = kvbase + t * 128;
    if (t < NT_KV - 1) {  // T14: issue next 128-tile's loads early
#pragma unroll
      for (int j = 0; j < 2; j++) {
        int kv0 = kvt + 128 + j * 64;
        kr[j][0] = *(const bf16x8*)(Kbase + (size_t)(kv0 + sr) * H + ss * 8);
        kr[j][1] = *(const bf16x8*)(Kbase + (size_t)(kv0 + sr1) * H + ss1 * 8);
        vr[j][0] = *(const bf16x8*)(Vbase + (size_t)sr * NCTX + kv0 + ss * 8);
        vr[j][1] = *(const bf16x8*)(Vbase + (size_t)sr1 * NCTX + kv0 + ss1 * 8);
      }
    }

    // QK^T on both sub-tiles (swapped operands; lane: q=lo, kv=j*64+nt*16+hi*4+r)
    f32x4 sc[2][4];
    __builtin_amdgcn_s_setprio(1);
#pragma unroll
    for (int j = 0; j < 2; j++)
#pragma unroll
      for (int nt = 0; nt < 4; nt++) {
        bf16x8 kf0 = *(const bf16x8*)((char*)Ks[j] + ((((nt * 16 + lo) * 128) + hi * 16) ^ swz));
        bf16x8 kf1 = *(const bf16x8*)((char*)Ks[j] + ((((nt * 16 + lo) * 128) + 64 + hi * 16) ^ swz));
        f32x4 z = (f32x4){0.f, 0.f, 0.f, 0.f};
        z = __builtin_amdgcn_mfma_f32_16x16x32_bf16(kf0, qf0, z, 0, 0, 0);
        sc[j][nt] = __builtin_amdgcn_mfma_f32_16x16x32_bf16(kf1, qf1, z, 0, 0, 0);
      }
    __builtin_amdgcn_s_setprio(0);

    // additive mask
    float pv[2][4][4];
#pragma unroll
    for (int j = 0; j < 2; j++)
#pragma unroll
      for (int nt = 0; nt < 4; nt++) {
        float4 mv = *(const float4*)(maskb + kvt + j * 64 + nt * 16 + hi * 4);
        pv[j][nt][0] = sc[j][nt][0] + mv.x;
        pv[j][nt][1] = sc[j][nt][1] + mv.y;
        pv[j][nt][2] = sc[j][nt][2] + mv.z;
        pv[j][nt][3] = sc[j][nt][3] + mv.w;
      }

    // ONE online-softmax reduce over all 32 values
    float gm[2];
#pragma unroll
    for (int j = 0; j < 2; j++) {
      float m0 = fmaxf(fmaxf(pv[j][0][0], pv[j][0][1]), fmaxf(pv[j][0][2], pv[j][0][3]));
      float m1 = fmaxf(fmaxf(pv[j][1][0], pv[j][1][1]), fmaxf(pv[j][1][2], pv[j][1][3]));
      float m2 = fmaxf(fmaxf(pv[j][2][0], pv[j][2][1]), fmaxf(pv[j][2][2], pv[j][2][3]));
      float m3 = fmaxf(fmaxf(pv[j][3][0], pv[j][3][1]), fmaxf(pv[j][3][2], pv[j][3][3]));
      gm[j] = fmaxf(fmaxf(m0, m1), fmaxf(m2, m3));
    }
    float x = fmaxf(gm[0], gm[1]);
    x = fmaxf(x, __shfl_xor(x, 16));
    x = fmaxf(x, __shfl_xor(x, 32));
    bool defer = __all((x <= mrow + 8.0f) && (mrow > -1e29f));
    float mn, scal = 1.f;
    if (defer) {
      mn = mrow;
    } else {
      mn = fmaxf(mrow, x);
      scal = __expf(mrow - mn);
      mrow = mn;
    }
    float rs = 0.f;
#pragma unroll
    for (int j = 0; j < 2; j++) {
      float rsp[4];
#pragma unroll
      for (int nt = 0; nt < 4; nt++) {
        float e0 = __expf(pv[j][nt][0] - mn);
        float e1 = __expf(pv[j][nt][1] - mn);
        float e2 = __expf(pv[j][nt][2] - mn);
        float e3 = __expf(pv[j][nt][3] - mn);
        pv[j][nt][0] = e0; pv[j][nt][1] = e1; pv[j][nt][2] = e2; pv[j][nt][3] = e3;
        rsp[nt] = (e0 + e1) + (e2 + e3);
      }
      rs += (rsp[0] + rsp[1]) + (rsp[2] + rsp[3]);
    }
    rs += __shfl_xor(rs, 16);
    rs += __shfl_xor(rs, 32);
    if (defer) {
      lrow += rs;
    } else {
      lrow = lrow * scal + rs;
      float sq0 = __shfl(scal, hi * 4 + 0);
      float sq1 = __shfl(scal, hi * 4 + 1);
      float sq2 = __shfl(scal, hi * 4 + 2);
      float sq3 = __shfl(scal, hi * 4 + 3);
#pragma unroll
      for (int d = 0; d < 4; d++) {
        oacc[d][0] *= sq0; oacc[d][1] *= sq1; oacc[d][2] *= sq2; oacc[d][3] *= sq3;
      }
    }

    // per sub-tile: P -> shared per-wave Ps, then PV (same-wave sequential, no barrier)
    __builtin_amdgcn_s_setprio(1);
#pragma unroll
    for (int j = 0; j < 2; j++) {
#pragma unroll
      for (int nt = 0; nt < 4; nt++) {
        uint2 pw;
        pw.x = cvt_pk_bf16(pv[j][nt][0], pv[j][nt][1]);
        pw.y = cvt_pk_bf16(pv[j][nt][2], pv[j][nt][3]);
        *(uint2*)((char*)Ps[w] + ((lo * 128 + (nt * 16 + hi * 4) * 2) ^ swz)) = pw;
      }
#pragma unroll
      for (int ks = 0; ks < 2; ks++) {
        bf16x8 pa = *(const bf16x8*)((char*)Ps[w] + ((lo * 128 + (ks * 64 + hi * 16)) ^ swz));
#pragma unroll
        for (int d = 0; d < 4; d++) {
          bf16x8 vf = *(const bf16x8*)((char*)Vs[j] + (((d * 16 + lo) * 128 + ks * 64 + hi * 16) ^ swz));
          oacc[d] = __builtin_amdgcn_mfma_f32_16x16x32_bf16(pa, vf, oacc[d], 0, 0, 0);
        }
      }
    }
    __builtin_amdgcn_s_setprio(0);

    if (t < NT_KV - 1) {
      __syncthreads();  // all waves done reading this 128-tile
#pragma unroll
      for (int j = 0; j < 2; j++) {
        *(bf16x8*)((char*)Ks[j] + wb0) = kr[j][0];
        *(bf16x8*)((char*)Ks[j] + wb1) = kr[j][1];
        *(bf16x8*)((char*)Vs[j] + wb0) = vr[j][0];
        *(bf16x8*)((char*)Vs[j] + wb1) = vr[j][1];
      }
      __syncthreads();  // writes visible before next iteration's reads
    }
  }

  int row0 = b * 512 + qt * 64 + w * 16 + hi * 4;
#pragma unroll
  for (int d = 0; d < 4; d++) {
#pragma unroll
    for (int r = 0; r < 4; r++)
      OPf[((size_t)p * 2048 + row0 + r) * 1024 + h * 64 + d * 16 + lo] = oacc[d][r];
  }
  if (hi == 0) {
    int qrow = b * 512 + qt * 64 + w * 16 + lo;
    mlf[(((size_t)p * 2048 + qrow) * 16 + h) * 2] = mrow;
    mlf[(((size_t)p * 2048 + qrow) * 16 + h) * 2 + 1] = lrow;
  }
}

__global__ void attn_combine(const float* __restrict__ OPf, const float* __restrict__ mlf,
                             ushort* __restrict__ O) {
  int idx = blockIdx.x * 256 + threadIdx.x;
  int btr = idx >> 8;
  int c4 = idx & 255;
  int h = c4 >> 4;
  float m0 = mlf[((size_t)btr * 16 + h) * 2];
  float l0 = mlf[((size_t)btr * 16 + h) * 2 + 1];
  float m1 = mlf[(((size_t)2048 + btr) * 16 + h) * 2];
  float l1 = mlf[(((size_t)2048 + btr) * 16 + h) * 2 + 1];
  float M = fmaxf(m0, m1);
  float a0 = __expf(m0 - M), a1 = __expf(m1 - M);
  float inv = 1.0f / (a0 * l0 + a1 * l1);
  float4 o0 = ((const float4*)OPf)[idx];
  float4 o1 = ((const float4*)OPf)[(size_t)524288 + idx];
  s16x4 r;
  r[0] = (short)f2b((a0 * o0.x + a1 * o1.x) * inv);
  r[1] = (short)f2b((a0 * o0.y + a1 * o1.y) * inv);
  r[2] = (short)f2b((a0 * o0.z + a1 * o1.z) * inv);
  r[3] = (short)f2b((a0 * o0.w + a1 * o1.w) * inv);
  ((s16x4*)O)[idx] = r;
}

// ---------------- launch ----------------

extern "C" void kernel_launch(void* const* d_in, const int* in_sizes, int n_in,
                              void* d_out, int out_size, void* d_ws, size_t ws_size,
                              hipStream_t stream) {
  const float* query = (const float*)d_in[0];
  const float* context = (const float*)d_in[1];
  const int* ids = (const int*)d_in[2];
  const int* curp = (const int*)d_in[3];
  const int* bars = (const int*)d_in[4];
  const float* Wq = (const float*)d_in[5];
  const float* bq = (const float*)d_in[6];
  const float* Wk = (const float*)d_in[7];
  const float* bk = (const float*)d_in[8];
  const float* Wv = (const float*)d_in[9];
  const float* bv = (const float*)d_in[10];
  const float* Wo = (const float*)d_in[11];
  const float* bo = (const float*)d_in[12];
  const float* iemb = (const float*)d_in[13];
  const float* bemb = (const float*)d_in[14];
  float* out = (float*)d_out;

  ushort* ws = (ushort*)d_ws;
  ushort* Wqb = ws;
  ushort* Wkb = Wqb + (1u << 20);
  ushort* Wvb = Wkb + (1u << 20);
  ushort* Wob = Wvb + (1u << 20);
  ushort* qin = Wob + (1u << 20);        // dead after proj -> mlf overlay
  ushort* ctxb = qin + (2u << 20);       // dead after proj -> OPf overlay
  ushort* Qb = ctxb + (8u << 20);
  ushort* Kb = Qb + (2u << 20);
  ushort* VTb = Kb + (8u << 20);
  ushort* AOb = VTb + (8u << 20);

  float* OPf = (float*)ctxb;  // 2 x 2048 x 1024 f32 = 16 MB
  float* mlf = (float*)qin;   // 2 x 2048 x 16 x 2 f32 = 512 KB
  float* maskf = out;         // d_out as scratch; overwritten by gemm_o at the end

  prep_all<<<2048, 256, 0, stream>>>(query, context, ids, curp, bars, iemb, bemb,
                                     Wq, Wk, Wv, Wo, qin, ctxb, Wqb, Wkb, Wvb, Wob, maskf);

  proj_k<<<1152, 256, 0, stream>>>(qin, ctxb, Wqb, Wkb, Wvb, bq, bk, bv, Qb, Kb, VTb);

  attn_k<<<1024, 256, 0, stream>>>(Qb, Kb, VTb, maskf, OPf, mlf);
  attn_combine<<<2048, 256, 0, stream>>>(OPf, mlf, AOb);

  gemm_o<<<dim3(8, 16), 256, 0, stream>>>(AOb, Wob, bo, out);
}